// Round 1
// baseline (158.823 us; speedup 1.0000x reference)
//
#include <hip/hip_runtime.h>

#define NB 8
#define CH 128
#define HV 64
#define WV 64
#define HO 128
#define WO 128
#define KK 9

// ======================= kernel A: attention (softmax) =======================
// v3: 2 px/thread (float2 guide loads), residual folded into staged weights.
// 512 blocks x 128 threads = 65536 threads x 2px = 131072 px; 1024 waves (4/CU)
__global__ __launch_bounds__(128)
void la_att(const float* __restrict__ guide,   // [8,128,128,128]
            const float* __restrict__ wconv,   // [9,128]
            const float* __restrict__ bconv,   // [9]
            float* __restrict__ att)           // [8,9,128,128] (workspace)
{
    __shared__ float s_wT[CH * 12];  // transposed weights, row stride 12 (16B rows)
    const int tid = threadIdx.x;
    for (int i = tid; i < KK * CH; i += 128) {
        int k = i >> 7;      // 0..8
        int c = i & 127;     // 0..127
        // fold conv_res residual (att += guide[:, :K]) into the weight matrix:
        // w'[k,c] = w[k,c] + (k==c)
        s_wT[c * 12 + k] = wconv[i] + ((k == c) ? 1.0f : 0.0f);
    }

    const int p  = (blockIdx.x * 128 + tid) * 2;   // even pixel index over (b, ho, wo)
    const int wo = p & 127;
    const int ho = (p >> 7) & 127;
    const int b  = p >> 14;

    const float* gpix = guide + ((size_t)b * CH) * (HO * WO) + ho * WO + wo;

    float a0[KK], a1[KK];
    #pragma unroll
    for (int k = 0; k < KK; ++k) {
        float bc = bconv[k];
        a0[k] = bc;
        a1[k] = bc;
    }
    __syncthreads();

    #pragma unroll 8
    for (int c = 0; c < CH; ++c) {
        float2 g = *(const float2*)(gpix + (size_t)c * (HO * WO));
        const float4* w4 = (const float4*)&s_wT[c * 12];
        float4 wa = w4[0];
        float4 wb = w4[1];
        float w8 = s_wT[c * 12 + 8];
        a0[0] += g.x * wa.x;  a1[0] += g.y * wa.x;
        a0[1] += g.x * wa.y;  a1[1] += g.y * wa.y;
        a0[2] += g.x * wa.z;  a1[2] += g.y * wa.z;
        a0[3] += g.x * wa.w;  a1[3] += g.y * wa.w;
        a0[4] += g.x * wb.x;  a1[4] += g.y * wb.x;
        a0[5] += g.x * wb.y;  a1[5] += g.y * wb.y;
        a0[6] += g.x * wb.z;  a1[6] += g.y * wb.z;
        a0[7] += g.x * wb.w;  a1[7] += g.y * wb.w;
        a0[8] += g.x * w8;    a1[8] += g.y * w8;
    }

    float m0 = a0[0], m1 = a1[0];
    #pragma unroll
    for (int k = 1; k < KK; ++k) { m0 = fmaxf(m0, a0[k]); m1 = fmaxf(m1, a1[k]); }
    float s0 = 0.f, s1 = 0.f;
    #pragma unroll
    for (int k = 0; k < KK; ++k) {
        a0[k] = __expf(a0[k] - m0); s0 += a0[k];
        a1[k] = __expf(a1[k] - m1); s1 += a1[k];
    }
    float r0 = 1.0f / s0, r1 = 1.0f / s1;

    float* apix = att + ((size_t)b * KK) * (HO * WO) + ho * WO + wo;
    #pragma unroll
    for (int k = 0; k < KK; ++k) {
        float2 rr; rr.x = a0[k] * r0; rr.y = a1[k] * r1;
        *(float2*)(apix + (size_t)k * (HO * WO)) = rr;
    }
}

// ======================= kernel B: weighted 3x3 gather =======================
// block = (b, 16-channel group, 16(ho) x 32(wo) out tile); 2048 blocks x 128 thr
// thread owns out quad (ho, wo..wo+3) -> float4 stores
// value tile 8x16, halo 10x18 staged per 8 channels, double-buffered (stride 19)
#define HS 190               // 10 * 19 per channel
__global__ __launch_bounds__(128, 4)
void la_gather(const float* __restrict__ value,  // [8,128,64,64]
               const float* __restrict__ att,    // [8,9,128,128]
               float* __restrict__ out)          // [8,128,128,128]
{
    __shared__ float s_halo[2][8 * HS];

    const int tid = threadIdx.x;
    const int blk = blockIdx.x;
    const int wt = blk & 3;               // wo tile (32 wide): 0..3
    const int ht = (blk >> 2) & 7;        // ho tile (16 tall): 0..7
    const int cg = (blk >> 5) & 7;        // channel group of 16: 0..7
    const int b  = blk >> 8;

    const int tlw = tid & 7;              // wo-quad 0..7
    const int tho = tid >> 3;             // 0..15
    const int ho = ht * 16 + tho;
    const int wo = wt * 32 + tlw * 4;

    // ---- att for 4 pixels (float4 per k), independent of staging ----
    const float* apix = att + ((size_t)b * KK) * (HO * WO) + ho * WO + wo;
    float a0[KK], a1[KK], a2[KK], a3[KK];
    #pragma unroll
    for (int k = 0; k < KK; ++k) {
        float4 av = *(const float4*)(apix + (size_t)k * (HO * WO));
        a0[k] = av.x; a1[k] = av.y; a2[k] = av.z; a3[k] = av.w;
    }

    const int c0 = cg * 16;
    const int h0 = ht * 8 - 1;            // halo origin (value coords)
    const int w0 = wt * 16 - 1;
    const float* vb = value + (size_t)b * CH * (HV * WV);

    // stage 8 channels (group g) into buffer bf
    auto stage = [&](int g, int bf) {
        const float* vc = vb + (size_t)(c0 + g * 8) * (HV * WV);
        for (int i = tid; i < 8 * 180; i += 128) {
            int cc = i / 180;
            int r  = i - cc * 180;
            int hr = r / 18;
            int wr = r - hr * 18;
            int hh = min(max(h0 + hr, 0), HV - 1);
            int ww = min(max(w0 + wr, 0), WV - 1);
            s_halo[bf][cc * HS + hr * 19 + wr] =
                vc[(size_t)cc * (HV * WV) + hh * WV + ww];
        }
    };

    stage(0, 0);

    const int lh = tho >> 1;              // local value row 0..7 (halo row lh..lh+2)
    const int lw = tlw * 2;               // local halo col base
    float* ob = out + (((size_t)b * CH + c0) * HO + ho) * WO + wo;

    #pragma unroll
    for (int g = 0; g < 2; ++g) {
        __syncthreads();
        if (g == 0) stage(1, 1);          // loads overlap compute of group 0
        const float* buf = s_halo[g];
        #pragma unroll
        for (int cc = 0; cc < 8; ++cc) {
            const float* hp = &buf[cc * HS + lh * 19 + lw];
            float v00 = hp[0],  v01 = hp[1],  v02 = hp[2],  v03 = hp[3];
            float v10 = hp[19], v11 = hp[20], v12 = hp[21], v13 = hp[22];
            float v20 = hp[38], v21 = hp[39], v22 = hp[40], v23 = hp[41];
            float r0 = v00*a0[0] + v01*a0[1] + v02*a0[2]
                     + v10*a0[3] + v11*a0[4] + v12*a0[5]
                     + v20*a0[6] + v21*a0[7] + v22*a0[8];
            float r1 = v00*a1[0] + v01*a1[1] + v02*a1[2]
                     + v10*a1[3] + v11*a1[4] + v12*a1[5]
                     + v20*a1[6] + v21*a1[7] + v22*a1[8];
            float r2 = v01*a2[0] + v02*a2[1] + v03*a2[2]
                     + v11*a2[3] + v12*a2[4] + v13*a2[5]
                     + v21*a2[6] + v22*a2[7] + v23*a2[8];
            float r3 = v01*a3[0] + v02*a3[1] + v03*a3[2]
                     + v11*a3[3] + v12*a3[4] + v13*a3[5]
                     + v21*a3[6] + v22*a3[7] + v23*a3[8];
            float4 rr; rr.x = r0; rr.y = r1; rr.z = r2; rr.w = r3;
            *(float4*)(ob + (size_t)(g * 8 + cc) * (HO * WO)) = rr;
        }
    }
}

// ================== fallback: proven single fused kernel (R1) ==================
#define CCH 8
__global__ __launch_bounds__(128)
void la_fused(const float* __restrict__ guide,
              const float* __restrict__ value,
              const float* __restrict__ wconv,
              const float* __restrict__ bconv,
              float* __restrict__ out)
{
    __shared__ float s_wT[CH * 12];
    __shared__ float s_haloF[CCH * 110];

    const int tid = threadIdx.x;
    const int blk = blockIdx.x;
    const int wt = blk & 7;
    const int ht = (blk >> 3) & 7;
    const int b  = blk >> 6;

    for (int i = tid; i < KK * CH; i += 128) {
        int k = i >> 7;
        int c = i & 127;
        s_wT[c * 12 + k] = wconv[i];
    }

    const int tlwp = tid & 7;
    const int tho  = tid >> 3;
    const int ho = ht * 16 + tho;
    const int wo = wt * 16 + tlwp * 2;

    const float* gpix = guide + (((size_t)b * CH) * HO + ho) * WO + wo;

    float att0[KK], att1[KK];
    #pragma unroll
    for (int k = 0; k < KK; ++k) {
        float2 g = *(const float2*)(gpix + (size_t)k * (HO * WO));
        float bc = bconv[k];
        att0[k] = bc + g.x;
        att1[k] = bc + g.y;
    }
    __syncthreads();

    #pragma unroll 4
    for (int c = 0; c < CH; ++c) {
        float2 g = *(const float2*)(gpix + (size_t)c * (HO * WO));
        const float4* wt4 = (const float4*)&s_wT[c * 12];
        float4 wa = wt4[0];
        float4 wb = wt4[1];
        float w8 = s_wT[c * 12 + 8];
        att0[0] += g.x * wa.x;  att1[0] += g.y * wa.x;
        att0[1] += g.x * wa.y;  att1[1] += g.y * wa.y;
        att0[2] += g.x * wa.z;  att1[2] += g.y * wa.z;
        att0[3] += g.x * wa.w;  att1[3] += g.y * wa.w;
        att0[4] += g.x * wb.x;  att1[4] += g.y * wb.x;
        att0[5] += g.x * wb.y;  att1[5] += g.y * wb.y;
        att0[6] += g.x * wb.z;  att1[6] += g.y * wb.z;
        att0[7] += g.x * wb.w;  att1[7] += g.y * wb.w;
        att0[8] += g.x * w8;    att1[8] += g.y * w8;
    }

    float m0 = att0[0], m1 = att1[0];
    #pragma unroll
    for (int k = 1; k < KK; ++k) { m0 = fmaxf(m0, att0[k]); m1 = fmaxf(m1, att1[k]); }
    float s0 = 0.f, s1 = 0.f;
    #pragma unroll
    for (int k = 0; k < KK; ++k) {
        att0[k] = __expf(att0[k] - m0); s0 += att0[k];
        att1[k] = __expf(att1[k] - m1); s1 += att1[k];
    }
    float r0 = 1.0f / s0, r1 = 1.0f / s1;
    #pragma unroll
    for (int k = 0; k < KK; ++k) { att0[k] *= r0; att1[k] *= r1; }

    const int h0 = ht * 8 - 1;
    const int w0 = wt * 8 - 1;
    const int lh = tho >> 1;
    const float* vb = value + (size_t)b * CH * (HV * WV);
    float* ob = out + (((size_t)b * CH) * HO + ho) * WO + wo;

    for (int c0 = 0; c0 < CH; c0 += CCH) {
        __syncthreads();
        for (int i = tid; i < CCH * 100; i += 128) {
            int cc = i / 100;
            int r  = i - cc * 100;
            int hr = r / 10;
            int wr = r - hr * 10;
            int hh = min(max(h0 + hr, 0), HV - 1);
            int ww = min(max(w0 + wr, 0), WV - 1);
            s_haloF[cc * 110 + hr * 11 + wr] =
                vb[(size_t)(c0 + cc) * (HV * WV) + hh * WV + ww];
        }
        __syncthreads();
        #pragma unroll
        for (int cc = 0; cc < CCH; ++cc) {
            const float* hp = &s_haloF[cc * 110 + lh * 11 + tlwp];
            float v, q0, q1;
            v = hp[0];  q0  = v * att0[0]; q1  = v * att1[0];
            v = hp[1];  q0 += v * att0[1]; q1 += v * att1[1];
            v = hp[2];  q0 += v * att0[2]; q1 += v * att1[2];
            v = hp[11]; q0 += v * att0[3]; q1 += v * att1[3];
            v = hp[12]; q0 += v * att0[4]; q1 += v * att1[4];
            v = hp[13]; q0 += v * att0[5]; q1 += v * att1[5];
            v = hp[22]; q0 += v * att0[6]; q1 += v * att1[6];
            v = hp[23]; q0 += v * att0[7]; q1 += v * att1[7];
            v = hp[24]; q0 += v * att0[8]; q1 += v * att1[8];
            float2 rr; rr.x = q0; rr.y = q1;
            *(float2*)(ob + (size_t)(c0 + cc) * (HO * WO)) = rr;
        }
    }
}

extern "C" void kernel_launch(void* const* d_in, const int* in_sizes, int n_in,
                              void* d_out, int out_size, void* d_ws, size_t ws_size,
                              hipStream_t stream) {
    const float* guide = (const float*)d_in[0];
    const float* value = (const float*)d_in[1];
    const float* wconv = (const float*)d_in[2];
    const float* bconv = (const float*)d_in[3];
    float* outp = (float*)d_out;
    (void)in_sizes; (void)n_in; (void)out_size;

    const size_t att_bytes = (size_t)NB * KK * HO * WO * sizeof(float);  // 4.72 MB
    if (ws_size >= att_bytes) {
        float* attp = (float*)d_ws;
        la_att<<<dim3(512), dim3(128), 0, stream>>>(guide, wconv, bconv, attp);
        la_gather<<<dim3(2048), dim3(128), 0, stream>>>(value, attp, outp);
    } else {
        la_fused<<<dim3(NB * 8 * 8), dim3(128), 0, stream>>>(guide, value, wconv, bconv, outp);
    }
}

// Round 2
// 155.397 us; speedup vs baseline: 1.0220x; 1.0220x over previous
//
#include <hip/hip_runtime.h>

#define NB 8
#define CH 128
#define HV 64
#define WV 64
#define HO 128
#define WO 128
#define KK 9

// ======================= kernel A: attention (softmax) =======================
// v4: no LDS at all. Weights are wave-uniform -> scalar loads (s_load) from
// global, consumed as SGPR operands by v_fmac. 1 px/thread, 256-thr blocks:
// 512 blocks x 256 threads = 131072 threads = 2048 waves (8/CU) — the round-0
// shape that empirically beat 2px/thread@4 waves/CU.
// Residual (att += guide[:, :K]) folded by peeling channels 0..8.
__global__ __launch_bounds__(256)
void la_att(const float* __restrict__ guide,   // [8,128,128,128]
            const float* __restrict__ wconv,   // [9,128]
            const float* __restrict__ bconv,   // [9]
            float* __restrict__ att)           // [8,9,128,128] (workspace)
{
    const int tid = threadIdx.x;
    const int p  = blockIdx.x * 256 + tid;   // pixel index over (b, ho, wo)
    const int wo = p & 127;
    const int ho = (p >> 7) & 127;
    const int b  = p >> 14;

    const float* gpix = guide + ((size_t)b * CH) * (HO * WO) + ho * WO + wo;

    float a[KK];
    #pragma unroll
    for (int k = 0; k < KK; ++k)
        a[k] = bconv[k];                     // uniform -> s_load

    // ---- peeled channels 0..8: conv + residual (a[c] += g), k==c at compile time
    #pragma unroll
    for (int c = 0; c < KK; ++c) {
        float g = gpix[(size_t)c * (HO * WO)];
        #pragma unroll
        for (int k = 0; k < KK; ++k)
            a[k] += g * wconv[k * CH + c];   // uniform index -> SGPR operand
        a[c] += g;
    }

    // ---- channels 9..127: pure conv, weights via scalar pipe (no LDS)
    #pragma unroll 8
    for (int c = KK; c < CH; ++c) {
        float g = gpix[(size_t)c * (HO * WO)];
        #pragma unroll
        for (int k = 0; k < KK; ++k)
            a[k] += g * wconv[k * CH + c];
    }

    float m = a[0];
    #pragma unroll
    for (int k = 1; k < KK; ++k) m = fmaxf(m, a[k]);
    float s = 0.f;
    #pragma unroll
    for (int k = 0; k < KK; ++k) { a[k] = __expf(a[k] - m); s += a[k]; }
    float r = 1.0f / s;

    float* apix = att + ((size_t)b * KK) * (HO * WO) + ho * WO + wo;
    #pragma unroll
    for (int k = 0; k < KK; ++k)
        apix[(size_t)k * (HO * WO)] = a[k] * r;
}

// ======================= kernel B: weighted 3x3 gather =======================
// (unchanged this round — preserve attribution for the A change)
// block = (b, 16-channel group, 16(ho) x 32(wo) out tile); 2048 blocks x 128 thr
// thread owns out quad (ho, wo..wo+3) -> float4 stores
// value tile 8x16, halo 10x18 staged per 8 channels, double-buffered (stride 19)
#define HS 190               // 10 * 19 per channel
__global__ __launch_bounds__(128, 4)
void la_gather(const float* __restrict__ value,  // [8,128,64,64]
               const float* __restrict__ att,    // [8,9,128,128]
               float* __restrict__ out)          // [8,128,128,128]
{
    __shared__ float s_halo[2][8 * HS];

    const int tid = threadIdx.x;
    const int blk = blockIdx.x;
    const int wt = blk & 3;               // wo tile (32 wide): 0..3
    const int ht = (blk >> 2) & 7;        // ho tile (16 tall): 0..7
    const int cg = (blk >> 5) & 7;        // channel group of 16: 0..7
    const int b  = blk >> 8;

    const int tlw = tid & 7;              // wo-quad 0..7
    const int tho = tid >> 3;             // 0..15
    const int ho = ht * 16 + tho;
    const int wo = wt * 32 + tlw * 4;

    // ---- att for 4 pixels (float4 per k), independent of staging ----
    const float* apix = att + ((size_t)b * KK) * (HO * WO) + ho * WO + wo;
    float a0[KK], a1[KK], a2[KK], a3[KK];
    #pragma unroll
    for (int k = 0; k < KK; ++k) {
        float4 av = *(const float4*)(apix + (size_t)k * (HO * WO));
        a0[k] = av.x; a1[k] = av.y; a2[k] = av.z; a3[k] = av.w;
    }

    const int c0 = cg * 16;
    const int h0 = ht * 8 - 1;            // halo origin (value coords)
    const int w0 = wt * 16 - 1;
    const float* vb = value + (size_t)b * CH * (HV * WV);

    // stage 8 channels (group g) into buffer bf
    auto stage = [&](int g, int bf) {
        const float* vc = vb + (size_t)(c0 + g * 8) * (HV * WV);
        for (int i = tid; i < 8 * 180; i += 128) {
            int cc = i / 180;
            int r  = i - cc * 180;
            int hr = r / 18;
            int wr = r - hr * 18;
            int hh = min(max(h0 + hr, 0), HV - 1);
            int ww = min(max(w0 + wr, 0), WV - 1);
            s_halo[bf][cc * HS + hr * 19 + wr] =
                vc[(size_t)cc * (HV * WV) + hh * WV + ww];
        }
    };

    stage(0, 0);

    const int lh = tho >> 1;              // local value row 0..7 (halo row lh..lh+2)
    const int lw = tlw * 2;               // local halo col base
    float* ob = out + (((size_t)b * CH + c0) * HO + ho) * WO + wo;

    #pragma unroll
    for (int g = 0; g < 2; ++g) {
        __syncthreads();
        if (g == 0) stage(1, 1);          // loads overlap compute of group 0
        const float* buf = s_halo[g];
        #pragma unroll
        for (int cc = 0; cc < 8; ++cc) {
            const float* hp = &buf[cc * HS + lh * 19 + lw];
            float v00 = hp[0],  v01 = hp[1],  v02 = hp[2],  v03 = hp[3];
            float v10 = hp[19], v11 = hp[20], v12 = hp[21], v13 = hp[22];
            float v20 = hp[38], v21 = hp[39], v22 = hp[40], v23 = hp[41];
            float r0 = v00*a0[0] + v01*a0[1] + v02*a0[2]
                     + v10*a0[3] + v11*a0[4] + v12*a0[5]
                     + v20*a0[6] + v21*a0[7] + v22*a0[8];
            float r1 = v00*a1[0] + v01*a1[1] + v02*a1[2]
                     + v10*a1[3] + v11*a1[4] + v12*a1[5]
                     + v20*a1[6] + v21*a1[7] + v22*a1[8];
            float r2 = v01*a2[0] + v02*a2[1] + v03*a2[2]
                     + v11*a2[3] + v12*a2[4] + v13*a2[5]
                     + v21*a2[6] + v22*a2[7] + v23*a2[8];
            float r3 = v01*a3[0] + v02*a3[1] + v03*a3[2]
                     + v11*a3[3] + v12*a3[4] + v13*a3[5]
                     + v21*a3[6] + v22*a3[7] + v23*a3[8];
            float4 rr; rr.x = r0; rr.y = r1; rr.z = r2; rr.w = r3;
            *(float4*)(ob + (size_t)(g * 8 + cc) * (HO * WO)) = rr;
        }
    }
}

// ================== fallback: proven single fused kernel (R1) ==================
#define CCH 8
__global__ __launch_bounds__(128)
void la_fused(const float* __restrict__ guide,
              const float* __restrict__ value,
              const float* __restrict__ wconv,
              const float* __restrict__ bconv,
              float* __restrict__ out)
{
    __shared__ float s_wT[CH * 12];
    __shared__ float s_haloF[CCH * 110];

    const int tid = threadIdx.x;
    const int blk = blockIdx.x;
    const int wt = blk & 7;
    const int ht = (blk >> 3) & 7;
    const int b  = blk >> 6;

    for (int i = tid; i < KK * CH; i += 128) {
        int k = i >> 7;
        int c = i & 127;
        s_wT[c * 12 + k] = wconv[i];
    }

    const int tlwp = tid & 7;
    const int tho  = tid >> 3;
    const int ho = ht * 16 + tho;
    const int wo = wt * 16 + tlwp * 2;

    const float* gpix = guide + (((size_t)b * CH) * HO + ho) * WO + wo;

    float att0[KK], att1[KK];
    #pragma unroll
    for (int k = 0; k < KK; ++k) {
        float2 g = *(const float2*)(gpix + (size_t)k * (HO * WO));
        float bc = bconv[k];
        att0[k] = bc + g.x;
        att1[k] = bc + g.y;
    }
    __syncthreads();

    #pragma unroll 4
    for (int c = 0; c < CH; ++c) {
        float2 g = *(const float2*)(gpix + (size_t)c * (HO * WO));
        const float4* wt4 = (const float4*)&s_wT[c * 12];
        float4 wa = wt4[0];
        float4 wb = wt4[1];
        float w8 = s_wT[c * 12 + 8];
        att0[0] += g.x * wa.x;  att1[0] += g.y * wa.x;
        att0[1] += g.x * wa.y;  att1[1] += g.y * wa.y;
        att0[2] += g.x * wa.z;  att1[2] += g.y * wa.z;
        att0[3] += g.x * wa.w;  att1[3] += g.y * wa.w;
        att0[4] += g.x * wb.x;  att1[4] += g.y * wb.x;
        att0[5] += g.x * wb.y;  att1[5] += g.y * wb.y;
        att0[6] += g.x * wb.z;  att1[6] += g.y * wb.z;
        att0[7] += g.x * wb.w;  att1[7] += g.y * wb.w;
        att0[8] += g.x * w8;    att1[8] += g.y * w8;
    }

    float m0 = att0[0], m1 = att1[0];
    #pragma unroll
    for (int k = 1; k < KK; ++k) { m0 = fmaxf(m0, att0[k]); m1 = fmaxf(m1, att1[k]); }
    float s0 = 0.f, s1 = 0.f;
    #pragma unroll
    for (int k = 0; k < KK; ++k) {
        att0[k] = __expf(att0[k] - m0); s0 += att0[k];
        att1[k] = __expf(att1[k] - m1); s1 += att1[k];
    }
    float r0 = 1.0f / s0, r1 = 1.0f / s1;
    #pragma unroll
    for (int k = 0; k < KK; ++k) { att0[k] *= r0; att1[k] *= r1; }

    const int h0 = ht * 8 - 1;
    const int w0 = wt * 8 - 1;
    const int lh = tho >> 1;
    const float* vb = value + (size_t)b * CH * (HV * WV);
    float* ob = out + (((size_t)b * CH) * HO + ho) * WO + wo;

    for (int c0 = 0; c0 < CH; c0 += CCH) {
        __syncthreads();
        for (int i = tid; i < CCH * 100; i += 128) {
            int cc = i / 100;
            int r  = i - cc * 100;
            int hr = r / 10;
            int wr = r - hr * 10;
            int hh = min(max(h0 + hr, 0), HV - 1);
            int ww = min(max(w0 + wr, 0), WV - 1);
            s_haloF[cc * 110 + hr * 11 + wr] =
                vb[(size_t)(c0 + cc) * (HV * WV) + hh * WV + ww];
        }
        __syncthreads();
        #pragma unroll
        for (int cc = 0; cc < CCH; ++cc) {
            const float* hp = &s_haloF[cc * 110 + lh * 11 + tlwp];
            float v, q0, q1;
            v = hp[0];  q0  = v * att0[0]; q1  = v * att1[0];
            v = hp[1];  q0 += v * att0[1]; q1 += v * att1[1];
            v = hp[2];  q0 += v * att0[2]; q1 += v * att1[2];
            v = hp[11]; q0 += v * att0[3]; q1 += v * att1[3];
            v = hp[12]; q0 += v * att0[4]; q1 += v * att1[4];
            v = hp[13]; q0 += v * att0[5]; q1 += v * att1[5];
            v = hp[22]; q0 += v * att0[6]; q1 += v * att1[6];
            v = hp[23]; q0 += v * att0[7]; q1 += v * att1[7];
            v = hp[24]; q0 += v * att0[8]; q1 += v * att1[8];
            float2 rr; rr.x = q0; rr.y = q1;
            *(float2*)(ob + (size_t)(c0 + cc) * (HO * WO)) = rr;
        }
    }
}

extern "C" void kernel_launch(void* const* d_in, const int* in_sizes, int n_in,
                              void* d_out, int out_size, void* d_ws, size_t ws_size,
                              hipStream_t stream) {
    const float* guide = (const float*)d_in[0];
    const float* value = (const float*)d_in[1];
    const float* wconv = (const float*)d_in[2];
    const float* bconv = (const float*)d_in[3];
    float* outp = (float*)d_out;
    (void)in_sizes; (void)n_in; (void)out_size;

    const size_t att_bytes = (size_t)NB * KK * HO * WO * sizeof(float);  // 4.72 MB
    if (ws_size >= att_bytes) {
        float* attp = (float*)d_ws;
        la_att<<<dim3(512), dim3(256), 0, stream>>>(guide, wconv, bconv, attp);
        la_gather<<<dim3(2048), dim3(128), 0, stream>>>(value, attp, outp);
    } else {
        la_fused<<<dim3(NB * 8 * 8), dim3(128), 0, stream>>>(guide, value, wconv, bconv, outp);
    }
}